// Round 4
// baseline (217.991 us; speedup 1.0000x reference)
//
#include <hip/hip_runtime.h>

// Problem constants (from reference setup_inputs)
#define BB   64          // batch
#define SS   512         // seq len
#define HH   768         // hidden dim
#define WW   256         // MAX_WORD_LEN (words per batch)
#define WE   300         // word-embedding dim
#define OUTD (HH + WE)   // 1068 output feature dim

#define WPB  8           // words per block
#define GPB  (WW / WPB)  // word-groups per batch row = 32

// R4: R3's 8-way load batching was DEFEATED by the compiler (VGPR_Count=36
// proves v[8]+acc[8] never coexisted): the scalar `if (r<cn[k])` predicates
// made 8 basic blocks and LLVM unswitched them back into sequential per-word
// loops. This version forces a SINGLE branch-free basic block in the round
// loop: clamped scalar addresses + arithmetic masks, loads unconditional.
//  - sk = clamp(lo[k]+r, 0, hi[k]-1): pure SGPR math (lo/hi/r all uniform),
//    always in-bounds; empty/finished words re-read an already-hot line
//    (L1 hit, no extra HBM).
//  - acc[k] += v[k] * mk (mk = r<cn[k] ? 1 : 0): no exec-mask churn.
//  => 8 independent float4 loads issued back-to-back per round: 8x in-flight
//     bytes per thread vs R0-R3.
__global__ __launch_bounds__(256)
void EmbeddingsModule_45311904973549_kernel(
    const float* __restrict__ hidden,     // [B, S, H]
    const float* __restrict__ w2v,        // [VOCAB, WE]
    const int*   __restrict__ token_ids,  // [B, S] sorted per row, in [0,W)
    const int*   __restrict__ word_ids,   // [B, W] in [0,VOCAB)
    float*       __restrict__ out)        // [B, W, OUTD]
{
    __shared__ int tk[SS];
    __shared__ int LB[WPB + 1];   // LB[k] = first s with tk[s] >= w0+k

    const int blk = blockIdx.x;           // 0 .. BB*GPB-1
    const int b   = blk / GPB;
    const int w0  = (blk % GPB) * WPB;
    const int tid = threadIdx.x;

    // ---- Phase 1: stage token row (512 ints, int2 per thread) + init bounds
    ((int2*)tk)[tid] = ((const int2*)(token_ids + (size_t)b * SS))[tid];
    if (tid <= WPB) LB[tid] = SS;         // default: word starts past the end
    __syncthreads();

    // ---- Phase 2: scatter segment starts for this block's 9 boundaries.
    // For position s with t=tk[s], tp=tk[s-1] (tp=-1 at s=0): every word w in
    // (tp, t] has lower_bound s. Each LB[k] is written by at most one thread.
    #pragma unroll
    for (int u = 0; u < 2; ++u) {
        const int s  = tid * 2 + u;
        const int t  = tk[s];
        const int tp = (s == 0) ? -1 : tk[s - 1];
        int klo = tp + 1 - w0; if (klo < 0)   klo = 0;
        int khi = t - w0;      if (khi > WPB) khi = WPB;
        for (int k = klo; k <= khi; ++k) LB[k] = s;
    }
    __syncthreads();

    if (tid < 192) {
        // ---- segment means: thread owns float4 column `tid` for 8 words.
        const float4* hrow = (const float4*)(hidden + (size_t)b * SS * HH);

        int lo[WPB], hi[WPB], cn[WPB];
        int maxcnt = 0;
        #pragma unroll
        for (int k = 0; k < WPB; ++k) {
            lo[k] = __builtin_amdgcn_readfirstlane(LB[k]);
            hi[k] = __builtin_amdgcn_readfirstlane(LB[k + 1]);
            cn[k] = hi[k] - lo[k];
            maxcnt = (cn[k] > maxcnt) ? cn[k] : maxcnt;
        }
        if (maxcnt > SS) maxcnt = SS;     // hard bound (defensive)

        float4 acc[WPB];
        #pragma unroll
        for (int k = 0; k < WPB; ++k) acc[k] = make_float4(0.f, 0.f, 0.f, 0.f);

        for (int r = 0; r < maxcnt; ++r) {
            // --- batch: 8 unconditional clamped loads (single basic block,
            //     scalar addresses) -> scheduler clusters them.
            float4 v[WPB];
            #pragma unroll
            for (int k = 0; k < WPB; ++k) {
                int sk = lo[k] + r;               // scalar
                int se = hi[k] - 1;               // scalar
                sk = (sk > se) ? se : sk;         // clamp to last row of word
                sk = (sk < 0)  ? 0  : sk;         // empty word -> row 0
                v[k] = hrow[(size_t)sk * (HH / 4) + tid];
            }
            // --- consume: masked accumulate (no branches)
            #pragma unroll
            for (int k = 0; k < WPB; ++k) {
                const float mk = (r < cn[k]) ? 1.0f : 0.0f;   // scalar
                acc[k].x = fmaf(v[k].x, mk, acc[k].x);
                acc[k].y = fmaf(v[k].y, mk, acc[k].y);
                acc[k].z = fmaf(v[k].z, mk, acc[k].z);
                acc[k].w = fmaf(v[k].w, mk, acc[k].w);
            }
        }

        #pragma unroll
        for (int k = 0; k < WPB; ++k) {
            const float inv = (cn[k] > 0) ? (1.0f / (float)cn[k]) : 0.0f;
            acc[k].x *= inv; acc[k].y *= inv; acc[k].z *= inv; acc[k].w *= inv;
            float4* orow = (float4*)(out + (size_t)(b * WW + w0 + k) * OUTD);
            orow[tid] = acc[k];           // out[b, w0+k, 0:768]
        }
    } else {
        // ---- w2v gather: 8 rows x 75 float4 with 64 threads, batched.
        const int t64 = tid - 192;
        const int* wp = word_ids + b * WW + w0;   // 32B-aligned (w0 % 8 == 0)
        const int4 wa = ((const int4*)wp)[0];
        const int4 wb = ((const int4*)wp)[1];
        const int wid[WPB] = {wa.x, wa.y, wa.z, wa.w, wb.x, wb.y, wb.z, wb.w};

        // main body: j = t64 (first 64 of 75 float4s): 8 loads then 8 stores
        float4 tmp[WPB];
        #pragma unroll
        for (int k = 0; k < WPB; ++k)
            tmp[k] = ((const float4*)(w2v + (size_t)wid[k] * WE))[t64];
        #pragma unroll
        for (int k = 0; k < WPB; ++k)
            ((float4*)(out + (size_t)(b * WW + w0 + k) * OUTD + HH))[t64] = tmp[k];

        // tail: j = 64 + t64 for t64 < 11
        if (t64 < (WE / 4 - 64)) {
            float4 t2[WPB];
            #pragma unroll
            for (int k = 0; k < WPB; ++k)
                t2[k] = ((const float4*)(w2v + (size_t)wid[k] * WE))[64 + t64];
            #pragma unroll
            for (int k = 0; k < WPB; ++k)
                ((float4*)(out + (size_t)(b * WW + w0 + k) * OUTD + HH))[64 + t64] = t2[k];
        }
    }
}

extern "C" void kernel_launch(void* const* d_in, const int* in_sizes, int n_in,
                              void* d_out, int out_size, void* d_ws, size_t ws_size,
                              hipStream_t stream) {
    const float* hidden    = (const float*)d_in[0];
    const float* w2v       = (const float*)d_in[1];
    const int*   token_ids = (const int*)d_in[2];
    const int*   word_ids  = (const int*)d_in[3];
    float*       out       = (float*)d_out;

    EmbeddingsModule_45311904973549_kernel<<<BB * GPB, 256, 0, stream>>>(
        hidden, w2v, token_ids, word_ids, out);
}

// Round 5
// 213.351 us; speedup vs baseline: 1.0217x; 1.0217x over previous
//
#include <hip/hip_runtime.h>

// Problem constants (from reference setup_inputs)
#define BB   64          // batch
#define SS   512         // seq len
#define HH   768         // hidden dim
#define WW   256         // MAX_WORD_LEN (words per batch)
#define WE   300         // word-embedding dim
#define OUTD (HH + WE)   // 1068 output feature dim

// A-blocks: token-centric streaming segment-mean
#define NR       8            // token ranges per batch row
#define TR       (SS / NR)    // 64 tokens per A-block
#define ABLOCKS  (BB * NR)    // 512
// B-blocks: pure w2v gather
#define WGPB     8            // word-groups per batch row
#define WPB_B    (WW / WGPB)  // 32 words per B-block
#define BBLOCKS  (BB * WGPB)  // 512

// R5: all previous rounds were latency-bound at ~2 TB/s because the hidden
// loads were entangled with per-word control flow -> compiler always found a
// pressure-cheaper serial schedule (R3: VGPR=36, R4: VGPR=32 prove v[8] and
// acc[8] never coexisted). This version makes the load stream STRUCTURALLY
// independent:
//   A-blocks stream a contiguous 64-token slab of hidden rows in batches of
//   8 (addresses = pure induction math), sched_barrier(0) pins the 8 loads
//   above the consume phase. Token boundaries are block-uniform (LDS token
//   row) -> flush/zero-fill logic is uniform scalar branching after loads.
//   Words partitioned by "word starts in my token range" (contiguous range
//   (tk[s0-1], tk[s1-1]], last block extends to 255); empty words zero-
//   filled in-stream. A writes out[...,0:768] of every word exactly once.
//   B-blocks do the pure w2v gather (out[...,768:1068]), 9-10 batched
//   independent float4 loads per thread.
__global__ __launch_bounds__(256)
void EmbeddingsModule_45311904973549_kernel(
    const float* __restrict__ hidden,     // [B, S, H]
    const float* __restrict__ w2v,        // [VOCAB, WE]
    const int*   __restrict__ token_ids,  // [B, S] sorted per row, in [0,W)
    const int*   __restrict__ word_ids,   // [B, W] in [0,VOCAB)
    float*       __restrict__ out)        // [B, W, OUTD]
{
    const int tid = threadIdx.x;

    if (blockIdx.x >= ABLOCKS) {
        // ================= B: pure w2v gather =================
        const int blk = blockIdx.x - ABLOCKS;
        const int b   = blk / WGPB;
        const int w   = (blk % WGPB) * WPB_B + (tid >> 3);  // 32 words x 8 lanes
        const int l   = tid & 7;
        const int wid = word_ids[b * WW + w];
        const float4* src = (const float4*)(w2v + (size_t)wid * WE);
        float4*       dst = (float4*)(out + (size_t)(b * WW + w) * OUTD + HH);
        float4 t[10];
        #pragma unroll
        for (int i = 0; i < 9; ++i) t[i] = src[l + 8 * i];   // j = 0..71
        if (l < 3) t[9] = src[72 + l];                       // j = 72..74
        #pragma unroll
        for (int i = 0; i < 9; ++i) dst[l + 8 * i] = t[i];
        if (l < 3) dst[72 + l] = t[9];
        return;
    }

    // ================= A: token-centric segment means =================
    __shared__ int tk[SS];
    __shared__ int LB[WW + 1];    // LB[k] = lower_bound(k) over this row

    const int b  = blockIdx.x / NR;
    const int r  = blockIdx.x % NR;
    const int s0 = r * TR;

    // stage token row (512 ints, int2 per thread) + init LB
    ((int2*)tk)[tid] = ((const int2*)(token_ids + (size_t)b * SS))[tid];
    LB[tid] = SS;
    if (tid == 0) LB[WW] = SS;
    __syncthreads();

    // scatter: position s with t=tk[s], tp=tk[s-1] sets LB[k]=s for k in (tp,t]
    #pragma unroll
    for (int u = 0; u < 2; ++u) {
        const int s  = tid * 2 + u;
        const int t  = tk[s];
        const int tp = (s == 0) ? -1 : tk[s - 1];
        for (int k = tp + 1; k <= t; ++k) LB[k] = s;
    }
    __syncthreads();

    // word range owned by this block: (w_prev, wlast]
    const int w_prev = (r == 0) ? -1 : tk[s0 - 1];
    const int wlast  = (r == NR - 1) ? (WW - 1) : tk[s0 + TR - 1];
    if (wlast == w_prev) return;                 // no words start in this range

    const int s_start = __builtin_amdgcn_readfirstlane(LB[w_prev + 1]);
    const int e       = __builtin_amdgcn_readfirstlane(LB[wlast + 1]);

    if (tid >= 192) return;                      // wave 3 done (staging only)

    float* const outb = out + (size_t)b * WW * OUTD;
    const float4 z4 = make_float4(0.f, 0.f, 0.f, 0.f);

    if (s_start >= SS) {                         // stream empty (only r==NR-1)
        for (int w = w_prev + 1; w <= wlast; ++w)
            ((float4*)(outb + (size_t)w * OUTD))[tid] = z4;
        return;
    }
    // leading empty words: (w_prev, tk[s_start])
    {
        const int wfirst = tk[s_start];
        for (int w = w_prev + 1; w < wfirst; ++w)
            ((float4*)(outb + (size_t)w * OUTD))[tid] = z4;
    }

    const float4* hrow = (const float4*)(hidden + (size_t)b * SS * HH);
    float4 acc = z4;
    int    cnt = 0;
    const int sb0 = s_start & ~7;                // align batches to 8 rows

    for (int sb = sb0; sb < e; sb += 8) {
        // --- 8 independent streaming loads (addresses: pure induction math)
        float4 v[8];
        #pragma unroll
        for (int j = 0; j < 8; ++j) {
            int s = sb + j; s = (s < e) ? s : (e - 1);   // clamp: in-bounds reread
            v[j] = hrow[(size_t)s * (HH / 4) + tid];
        }
        // batch token values (LDS, broadcast reads; issued under load shadow)
        int tok[9];
        #pragma unroll
        for (int j = 0; j < 9; ++j) {
            int s = sb + j; tok[j] = tk[(s < SS) ? s : (SS - 1)];
        }
        __builtin_amdgcn_sched_barrier(0);   // consume may not move above this
        // --- consume: accumulate + uniform flush/zero-fill
        #pragma unroll
        for (int j = 0; j < 8; ++j) {
            const int s = sb + j;
            if (s >= s_start && s < e) {
                acc.x += v[j].x; acc.y += v[j].y; acc.z += v[j].z; acc.w += v[j].w;
                ++cnt;
                const bool fl = (s + 1 == e) || (tok[j + 1] != tok[j]);
                if (fl) {
                    const float inv = 1.0f / (float)cnt;
                    float4 o = make_float4(acc.x * inv, acc.y * inv,
                                           acc.z * inv, acc.w * inv);
                    ((float4*)(outb + (size_t)tok[j] * OUTD))[tid] = o;
                    acc = z4; cnt = 0;
                    // trailing empty words up to next token's word (or block end)
                    const int wnext = (s + 1 < e) ? tok[j + 1] : (wlast + 1);
                    for (int w = tok[j] + 1; w < wnext; ++w)
                        ((float4*)(outb + (size_t)w * OUTD))[tid] = z4;
                }
            }
        }
    }
}

extern "C" void kernel_launch(void* const* d_in, const int* in_sizes, int n_in,
                              void* d_out, int out_size, void* d_ws, size_t ws_size,
                              hipStream_t stream) {
    const float* hidden    = (const float*)d_in[0];
    const float* w2v       = (const float*)d_in[1];
    const int*   token_ids = (const int*)d_in[2];
    const int*   word_ids  = (const int*)d_in[3];
    float*       out       = (float*)d_out;

    EmbeddingsModule_45311904973549_kernel<<<ABLOCKS + BBLOCKS, 256, 0, stream>>>(
        hidden, w2v, token_ids, word_ids, out);
}